// Round 1
// baseline (386.802 us; speedup 1.0000x reference)
//
#include <hip/hip_runtime.h>
#include <math.h>

#define TT 40          // total query tokens (sum of q_seqlens)
#define NB 16          // batch
#define HQn 16         // query heads
#define HKn 8          // kv heads
#define Gn 2           // GQA group
#define Dn 256         // head dim
#define HID 3072
#define QKV_COLS 8192  // 4096 + 2048 + 2048
#define NCHUNK 16
#define CHUNKT 128

// ---------------- K1: QKV partial GEMM ----------------
// grid 512 = 32 col-tiles(256) * 16 k-splits(192), block 256
__global__ __launch_bounds__(256) void k1_qkv_gemm(
    const float* __restrict__ hs, const float* __restrict__ Wq,
    const float* __restrict__ Wk, const float* __restrict__ Wv,
    float* __restrict__ part1) {
  const int tile = blockIdx.x & 31;
  const int ks = blockIdx.x >> 5;
  const int c0 = tile << 8;
  const float* W; int ld, cw0;
  if (tile < 16)      { W = Wq; ld = 4096; cw0 = c0; }
  else if (tile < 24) { W = Wk; ld = 2048; cw0 = c0 - 4096; }
  else                { W = Wv; ld = 2048; cw0 = c0 - 6144; }
  const int kbase = ks * 192;
  const int cq = (threadIdx.x & 63) << 2;
  const int r0 = (threadIdx.x >> 6) * 10;
  __shared__ float h_lds[64][40];
  float acc[10][4];
#pragma unroll
  for (int r = 0; r < 10; ++r) { acc[r][0]=0.f; acc[r][1]=0.f; acc[r][2]=0.f; acc[r][3]=0.f; }
  for (int kc = 0; kc < 192; kc += 64) {
    __syncthreads();
    for (int i = threadIdx.x; i < 2560; i += 256) {
      int kk = i / 40, t = i - kk * 40;
      h_lds[kk][t] = hs[t * HID + kbase + kc + kk];
    }
    __syncthreads();
    const float* wp = W + (size_t)(kbase + kc) * ld + cw0 + cq;
#pragma unroll 4
    for (int kk = 0; kk < 64; ++kk) {
      float4 w4 = *reinterpret_cast<const float4*>(wp + (size_t)kk * ld);
#pragma unroll
      for (int r = 0; r < 10; ++r) {
        float h = h_lds[kk][r0 + r];
        acc[r][0] = fmaf(h, w4.x, acc[r][0]);
        acc[r][1] = fmaf(h, w4.y, acc[r][1]);
        acc[r][2] = fmaf(h, w4.z, acc[r][2]);
        acc[r][3] = fmaf(h, w4.w, acc[r][3]);
      }
    }
  }
#pragma unroll
  for (int r = 0; r < 10; ++r) {
    int t = r0 + r;
    float4 v = make_float4(acc[r][0], acc[r][1], acc[r][2], acc[r][3]);
    *reinterpret_cast<float4*>(&part1[(size_t)(ks * TT + t) * QKV_COLS + c0 + cq]) = v;
  }
}

// ---------------- K2: k-split reduce + RoPE ----------------
// grid 1280 = 40 tokens * 32 tiles, block 256
__global__ __launch_bounds__(256) void k2_reduce_rope(
    const float* __restrict__ part1, const float* __restrict__ inv_freq,
    const int* __restrict__ pos_ids,
    float* __restrict__ qbuf, float* __restrict__ kbuf, float* __restrict__ vbuf) {
  const int t = blockIdx.x >> 5;
  const int tile = blockIdx.x & 31;
  const int c = (tile << 8) + threadIdx.x;
  float s = 0.f;
#pragma unroll
  for (int ks = 0; ks < 16; ++ks) s += part1[(size_t)(ks * TT + t) * QKV_COLS + c];
  __shared__ float sl[256];
  sl[threadIdx.x] = s;
  __syncthreads();
  if (tile < 24) {   // q or k head: apply neox RoPE
    const int d = threadIdx.x;
    const int d2 = d & 127;
    float fr = (float)pos_ids[t] * inv_freq[d2];
    float cs = cosf(fr), sn = sinf(fr);
    float v = (d < 128) ? (sl[d] * cs - sl[d + 128] * sn)
                        : (sl[d] * cs + sl[d - 128] * sn);
    if (tile < 16) qbuf[t * 4096 + (tile << 8) + d] = v * 0.0625f;  // fold 1/sqrt(D)
    else           kbuf[t * 2048 + ((tile - 16) << 8) + d] = v;
  } else {
    vbuf[t * 2048 + ((tile - 24) << 8) + threadIdx.x] = s;
  }
}

// ---------------- K3: flash-decode attention partials ----------------
// grid 2048 = b(16)*hk(8)*chunk(16 of 128 toks), block 256 (4 waves x 32 toks)
__global__ __launch_bounds__(256) void k3_attn_partial(
    const float* __restrict__ qbuf, const float* __restrict__ kbuf,
    const float* __restrict__ vbuf, const float* __restrict__ k_cache,
    const float* __restrict__ v_cache, const int* __restrict__ blk_off,
    const int* __restrict__ q_start, const int* __restrict__ q_lens,
    const int* __restrict__ kv_lens,
    float* __restrict__ part_o, float* __restrict__ part_ml) {
  const int chunk = blockIdx.x & 15;
  const int hk = (blockIdx.x >> 4) & 7;
  const int b = blockIdx.x >> 7;
  const int kv_len = kv_lens[b];
  const int cs0 = chunk * CHUNKT;
  if (cs0 >= kv_len) return;
  const int q_cnt = q_lens[b];
  const int hist = kv_len - q_cnt;
  const int q0 = q_start[b];
  const int nq = q_cnt * 2;

  __shared__ float q_lds[8][256];
  __shared__ float o_lds[4][8][256];
  __shared__ float ml_lds[4][8][2];

  for (int i = threadIdx.x; i < 2048; i += 256) {
    int qv = i >> 8, d = i & 255;
    float v = 0.f;
    if (qv < nq) {
      int qtok = qv >> 1, g = qv & 1;
      v = qbuf[(q0 + qtok) * 4096 + (hk * Gn + g) * 256 + d];
    }
    q_lds[qv][d] = v;
  }
  __syncthreads();

  const int w = threadIdx.x >> 6;
  const int lane = threadIdx.x & 63;
  float4 qf[8];
#pragma unroll
  for (int qv = 0; qv < 8; ++qv)
    qf[qv] = *reinterpret_cast<const float4*>(&q_lds[qv][lane << 2]);

  float m[8], l[8];
  float4 acc[8];
#pragma unroll
  for (int qv = 0; qv < 8; ++qv) {
    m[qv] = -1e30f; l[qv] = 0.f;
    acc[qv] = make_float4(0.f, 0.f, 0.f, 0.f);
  }

  const int sBeg = cs0 + w * 32;
  const int sEnd = min(cs0 + (w + 1) * 32, kv_len);
  for (int s = sBeg; s < sEnd; ++s) {
    const float *krow, *vrow;
    if (s < hist) {
      int blk = blk_off[(b << 5) + (s >> 6)];
      size_t base = (((size_t)blk * 64 + (s & 63)) * HKn + hk) << 8;
      krow = k_cache + base; vrow = v_cache + base;
    } else {
      size_t base = ((size_t)(q0 + s - hist) * HKn + hk) << 8;
      krow = kbuf + base; vrow = vbuf + base;
    }
    float4 kf = *reinterpret_cast<const float4*>(krow + (lane << 2));
    float4 vf = *reinterpret_cast<const float4*>(vrow + (lane << 2));
    float sc[8];
#pragma unroll
    for (int qv = 0; qv < 8; ++qv)
      sc[qv] = qf[qv].x * kf.x + qf[qv].y * kf.y + qf[qv].z * kf.z + qf[qv].w * kf.w;
#pragma unroll
    for (int qv = 0; qv < 8; ++qv) {
      sc[qv] += __shfl_xor(sc[qv], 32);
      sc[qv] += __shfl_xor(sc[qv], 16);
      sc[qv] += __shfl_xor(sc[qv], 8);
      sc[qv] += __shfl_xor(sc[qv], 4);
      sc[qv] += __shfl_xor(sc[qv], 2);
      sc[qv] += __shfl_xor(sc[qv], 1);
    }
    const int smh = s - hist;  // valid for qvec iff smh <= qtok (causal)
#pragma unroll
    for (int qv = 0; qv < 8; ++qv) {
      if (qv < nq && smh <= (qv >> 1)) {   // wave-uniform
        float sco = sc[qv];
        if (sco > m[qv]) {                 // wave-uniform
          float corr = __expf(m[qv] - sco);
          m[qv] = sco;
          l[qv] *= corr;
          acc[qv].x *= corr; acc[qv].y *= corr;
          acc[qv].z *= corr; acc[qv].w *= corr;
        }
        float p = __expf(sco - m[qv]);
        l[qv] += p;
        acc[qv].x = fmaf(p, vf.x, acc[qv].x);
        acc[qv].y = fmaf(p, vf.y, acc[qv].y);
        acc[qv].z = fmaf(p, vf.z, acc[qv].z);
        acc[qv].w = fmaf(p, vf.w, acc[qv].w);
      }
    }
  }
  // wave results -> LDS
#pragma unroll
  for (int qv = 0; qv < 8; ++qv)
    *reinterpret_cast<float4*>(&o_lds[w][qv][lane << 2]) = acc[qv];
  if (lane == 0) {
#pragma unroll
    for (int qv = 0; qv < 8; ++qv) {
      ml_lds[w][qv][0] = m[qv];
      ml_lds[w][qv][1] = l[qv];
    }
  }
  __syncthreads();
  // combine 4 waves -> one partial per (chunk, qvec)
  const int d = threadIdx.x;
  for (int qv = 0; qv < nq; ++qv) {
    float m0 = ml_lds[0][qv][0], m1 = ml_lds[1][qv][0];
    float m2 = ml_lds[2][qv][0], m3 = ml_lds[3][qv][0];
    float M = fmaxf(fmaxf(m0, m1), fmaxf(m2, m3));
    float e0 = __expf(m0 - M), e1 = __expf(m1 - M);
    float e2 = __expf(m2 - M), e3 = __expf(m3 - M);
    float o = e0 * o_lds[0][qv][d] + e1 * o_lds[1][qv][d]
            + e2 * o_lds[2][qv][d] + e3 * o_lds[3][qv][d];
    int pidx = (((b * HKn + hk) * NCHUNK + chunk) << 3) + qv;
    part_o[(size_t)pidx * 256 + d] = o;
    if (d == 0) {
      float L = e0 * ml_lds[0][qv][1] + e1 * ml_lds[1][qv][1]
              + e2 * ml_lds[2][qv][1] + e3 * ml_lds[3][qv][1];
      part_ml[pidx * 2] = M;
      part_ml[pidx * 2 + 1] = L;
    }
  }
}

// ---------------- K4: combine chunk partials ----------------
// grid 1024 = b(16)*qtok(4)*h(16), block 64
__global__ __launch_bounds__(64) void k4_attn_reduce(
    const float* __restrict__ part_o, const float* __restrict__ part_ml,
    const int* __restrict__ q_start, const int* __restrict__ q_lens,
    const int* __restrict__ kv_lens, float* __restrict__ attn_out) {
  const int h = blockIdx.x & 15;
  const int qtok = (blockIdx.x >> 4) & 3;
  const int b = blockIdx.x >> 6;
  const int q_cnt = q_lens[b];
  if (qtok >= q_cnt) return;
  const int kv_len = kv_lens[b];
  const int nparts = (kv_len + CHUNKT - 1) >> 7;
  const int qv = qtok * 2 + (h & 1);
  const int hk = h >> 1;
  const int lane = threadIdx.x;
  const int pbase = ((b * HKn + hk) * NCHUNK) << 3;
  float M = -1e30f;
  for (int i = 0; i < nparts; ++i)
    M = fmaxf(M, part_ml[(pbase + (i << 3) + qv) * 2]);
  float4 o = make_float4(0.f, 0.f, 0.f, 0.f);
  float L = 0.f;
  for (int i = 0; i < nparts; ++i) {
    int pidx = pbase + (i << 3) + qv;
    float corr = __expf(part_ml[pidx * 2] - M);
    L += corr * part_ml[pidx * 2 + 1];
    float4 pv = *reinterpret_cast<const float4*>(&part_o[(size_t)pidx * 256 + (lane << 2)]);
    o.x = fmaf(corr, pv.x, o.x);
    o.y = fmaf(corr, pv.y, o.y);
    o.z = fmaf(corr, pv.z, o.z);
    o.w = fmaf(corr, pv.w, o.w);
  }
  float inv = 1.0f / L;
  int tr = q_start[b] + qtok;
  float4 res = make_float4(o.x * inv, o.y * inv, o.z * inv, o.w * inv);
  *reinterpret_cast<float4*>(&attn_out[((size_t)tr * HQn + h) * 256 + (lane << 2)]) = res;
}

// ---------------- K5: output GEMM partial (attn @ Wo) ----------------
// grid 384 = 12 col-tiles(256) * 32 k-splits(128), block 256
__global__ __launch_bounds__(256) void k5_out_gemm(
    const float* __restrict__ ain, const float* __restrict__ Wo,
    float* __restrict__ part2) {
  const int tile = blockIdx.x % 12;
  const int ks = blockIdx.x / 12;
  const int c0 = tile << 8;
  const int kbase = ks << 7;
  const int cq = (threadIdx.x & 63) << 2;
  const int r0 = (threadIdx.x >> 6) * 10;
  __shared__ float h_lds[64][40];
  float acc[10][4];
#pragma unroll
  for (int r = 0; r < 10; ++r) { acc[r][0]=0.f; acc[r][1]=0.f; acc[r][2]=0.f; acc[r][3]=0.f; }
  for (int kc = 0; kc < 128; kc += 64) {
    __syncthreads();
    for (int i = threadIdx.x; i < 2560; i += 256) {
      int kk = i / 40, t = i - kk * 40;
      h_lds[kk][t] = ain[(size_t)t * 4096 + kbase + kc + kk];
    }
    __syncthreads();
    const float* wp = Wo + (size_t)(kbase + kc) * 3072 + c0 + cq;
#pragma unroll 4
    for (int kk = 0; kk < 64; ++kk) {
      float4 w4 = *reinterpret_cast<const float4*>(wp + (size_t)kk * 3072);
#pragma unroll
      for (int r = 0; r < 10; ++r) {
        float h = h_lds[kk][r0 + r];
        acc[r][0] = fmaf(h, w4.x, acc[r][0]);
        acc[r][1] = fmaf(h, w4.y, acc[r][1]);
        acc[r][2] = fmaf(h, w4.z, acc[r][2]);
        acc[r][3] = fmaf(h, w4.w, acc[r][3]);
      }
    }
  }
#pragma unroll
  for (int r = 0; r < 10; ++r) {
    int t = r0 + r;
    float4 v = make_float4(acc[r][0], acc[r][1], acc[r][2], acc[r][3]);
    *reinterpret_cast<float4*>(&part2[(size_t)(ks * TT + t) * 3072 + c0 + cq]) = v;
  }
}

// ---------------- K6: final k-split reduce -> d_out ----------------
// grid 480, block 256  (40*3072 = 122880 outputs)
__global__ __launch_bounds__(256) void k6_final_reduce(
    const float* __restrict__ part2, float* __restrict__ out) {
  const int idx = blockIdx.x * 256 + threadIdx.x;
  float s = 0.f;
#pragma unroll
  for (int ks = 0; ks < 32; ++ks) s += part2[(size_t)ks * 122880 + idx];
  out[idx] = s;
}

extern "C" void kernel_launch(void* const* d_in, const int* in_sizes, int n_in,
                              void* d_out, int out_size, void* d_ws, size_t ws_size,
                              hipStream_t stream) {
  const float* hs       = (const float*)d_in[0];
  const float* Wq       = (const float*)d_in[1];
  const float* Wk       = (const float*)d_in[2];
  const float* Wv       = (const float*)d_in[3];
  const float* Wo       = (const float*)d_in[4];
  const float* k_cache  = (const float*)d_in[5];
  const float* v_cache  = (const float*)d_in[6];
  const float* inv_freq = (const float*)d_in[7];
  const int*   pos_ids  = (const int*)d_in[8];
  const int*   q_start  = (const int*)d_in[9];
  const int*   q_lens   = (const int*)d_in[10];
  const int*   kv_lens  = (const int*)d_in[11];
  const int*   blk_off  = (const int*)d_in[12];

  float* ws = (float*)d_ws;
  float* qbuf     = ws;                 // 40*4096          = 163840
  float* kbuf     = ws + 163840;        // 40*2048          =  81920
  float* vbuf     = ws + 245760;        // 40*2048          =  81920
  float* attn_out = ws + 327680;        // 40*4096          = 163840
  float* big      = ws + 491520;        // reused region (5242880 floats)
  float* part1    = big;                // 16*40*8192
  float* part_o   = big;                // 16384*256
  float* part_ml  = big + 4194304;      // 16384*2
  float* part2    = big;                // 32*40*3072
  float* out      = (float*)d_out;

  k1_qkv_gemm<<<512, 256, 0, stream>>>(hs, Wq, Wk, Wv, part1);
  k2_reduce_rope<<<1280, 256, 0, stream>>>(part1, inv_freq, pos_ids, qbuf, kbuf, vbuf);
  k3_attn_partial<<<2048, 256, 0, stream>>>(qbuf, kbuf, vbuf, k_cache, v_cache,
                                            blk_off, q_start, q_lens, kv_lens,
                                            part_o, part_ml);
  k4_attn_reduce<<<1024, 64, 0, stream>>>(part_o, part_ml, q_start, q_lens,
                                          kv_lens, attn_out);
  k5_out_gemm<<<384, 256, 0, stream>>>(attn_out, Wo, part2);
  k6_final_reduce<<<480, 256, 0, stream>>>(part2, out);
}

// Round 2
// 359.299 us; speedup vs baseline: 1.0765x; 1.0765x over previous
//
#include <hip/hip_runtime.h>
#include <math.h>

#define TT 40          // total query tokens (sum of q_seqlens)
#define NB 16          // batch
#define HQn 16         // query heads
#define HKn 8          // kv heads
#define Gn 2           // GQA group
#define Dn 256         // head dim
#define HID 3072
#define QKV_COLS 8192  // 4096 + 2048 + 2048
#define NCHUNK 16
#define CHUNKT 128

// ---------------- K1: QKV partial GEMM ----------------
// grid 512 = 32 col-tiles(256) * 16 k-splits(192), block 256
__global__ __launch_bounds__(256) void k1_qkv_gemm(
    const float* __restrict__ hs, const float* __restrict__ Wq,
    const float* __restrict__ Wk, const float* __restrict__ Wv,
    float* __restrict__ part1) {
  const int tile = blockIdx.x & 31;
  const int ks = blockIdx.x >> 5;
  const int c0 = tile << 8;
  const float* W; int ld, cw0;
  if (tile < 16)      { W = Wq; ld = 4096; cw0 = c0; }
  else if (tile < 24) { W = Wk; ld = 2048; cw0 = c0 - 4096; }
  else                { W = Wv; ld = 2048; cw0 = c0 - 6144; }
  const int kbase = ks * 192;
  const int cq = (threadIdx.x & 63) << 2;
  const int r0 = (threadIdx.x >> 6) * 10;
  __shared__ float h_lds[64][40];
  float acc[10][4];
#pragma unroll
  for (int r = 0; r < 10; ++r) { acc[r][0]=0.f; acc[r][1]=0.f; acc[r][2]=0.f; acc[r][3]=0.f; }
  for (int kc = 0; kc < 192; kc += 64) {
    __syncthreads();
    for (int i = threadIdx.x; i < 2560; i += 256) {
      int kk = i / 40, t = i - kk * 40;
      h_lds[kk][t] = hs[t * HID + kbase + kc + kk];
    }
    __syncthreads();
    const float* wp = W + (size_t)(kbase + kc) * ld + cw0 + cq;
#pragma unroll 4
    for (int kk = 0; kk < 64; ++kk) {
      float4 w4 = *reinterpret_cast<const float4*>(wp + (size_t)kk * ld);
#pragma unroll
      for (int r = 0; r < 10; ++r) {
        float h = h_lds[kk][r0 + r];
        acc[r][0] = fmaf(h, w4.x, acc[r][0]);
        acc[r][1] = fmaf(h, w4.y, acc[r][1]);
        acc[r][2] = fmaf(h, w4.z, acc[r][2]);
        acc[r][3] = fmaf(h, w4.w, acc[r][3]);
      }
    }
  }
#pragma unroll
  for (int r = 0; r < 10; ++r) {
    int t = r0 + r;
    float4 v = make_float4(acc[r][0], acc[r][1], acc[r][2], acc[r][3]);
    *reinterpret_cast<float4*>(&part1[(size_t)(ks * TT + t) * QKV_COLS + c0 + cq]) = v;
  }
}

// ---------------- K2: k-split reduce + RoPE ----------------
// grid 1280 = 40 tokens * 32 tiles, block 256
__global__ __launch_bounds__(256) void k2_reduce_rope(
    const float* __restrict__ part1, const float* __restrict__ inv_freq,
    const int* __restrict__ pos_ids,
    float* __restrict__ qbuf, float* __restrict__ kbuf, float* __restrict__ vbuf) {
  const int t = blockIdx.x >> 5;
  const int tile = blockIdx.x & 31;
  const int c = (tile << 8) + threadIdx.x;
  float s = 0.f;
#pragma unroll
  for (int ks = 0; ks < 16; ++ks) s += part1[(size_t)(ks * TT + t) * QKV_COLS + c];
  __shared__ float sl[256];
  sl[threadIdx.x] = s;
  __syncthreads();
  if (tile < 24) {   // q or k head: apply neox RoPE
    const int d = threadIdx.x;
    const int d2 = d & 127;
    float fr = (float)pos_ids[t] * inv_freq[d2];
    float cs = cosf(fr), sn = sinf(fr);
    float v = (d < 128) ? (sl[d] * cs - sl[d + 128] * sn)
                        : (sl[d] * cs + sl[d - 128] * sn);
    if (tile < 16) qbuf[t * 4096 + (tile << 8) + d] = v * 0.0625f;  // fold 1/sqrt(D)
    else           kbuf[t * 2048 + ((tile - 16) << 8) + d] = v;
  } else {
    vbuf[t * 2048 + ((tile - 24) << 8) + threadIdx.x] = s;
  }
}

// ---------------- K3: flash-decode attention partials (3-phase, shuffle-light) ----
// grid 2048 = b(16)*hk(8)*chunk(16 of 128 toks), block 256 (4 waves)
__global__ __launch_bounds__(256) void k3_attn_partial(
    const float* __restrict__ qbuf, const float* __restrict__ kbuf,
    const float* __restrict__ vbuf, const float* __restrict__ k_cache,
    const float* __restrict__ v_cache, const int* __restrict__ blk_off,
    const int* __restrict__ q_start, const int* __restrict__ q_lens,
    const int* __restrict__ kv_lens,
    float* __restrict__ part_o, float* __restrict__ part_ml) {
  const int chunk = blockIdx.x & 15;
  const int hk = (blockIdx.x >> 4) & 7;
  const int b = blockIdx.x >> 7;
  const int kv_len = kv_lens[b];
  const int cs0 = chunk * CHUNKT;
  if (cs0 >= kv_len) return;
  const int q_cnt = q_lens[b];
  const int hist = kv_len - q_cnt;
  const int q0 = q_start[b];
  const int nq = q_cnt * 2;

  __shared__ float S_lds[128][8];     // scores -> then p values (in place)
  __shared__ float red[32][8];
  __shared__ float Mg[8];
  __shared__ float o_lds[4][8][256];

  const int tid = threadIdx.x;
  const int w = tid >> 6;
  const int lane = tid & 63;

  // init scores to -inf (unwritten tail rows must be masked)
#pragma unroll
  for (int i = tid; i < 1024; i += 256) ((float*)S_lds)[i] = -1e30f;

  // ---- phase 1: scores. lane = qv(0..7) + 8*dgrp(0..7); wave handles 32 tokens.
  const int qv = lane & 7;
  const int dgrp = lane >> 3;
  const int qtok = min(qv >> 1, q_cnt - 1);
  const int g = qv & 1;
  float4 qf[8];
  {
    const float* qp = qbuf + (size_t)(q0 + qtok) * 4096 + (hk * Gn + g) * 256 + dgrp * 32;
#pragma unroll
    for (int j = 0; j < 8; ++j)
      qf[j] = *reinterpret_cast<const float4*>(qp + j * 4);
  }
  __syncthreads();

  const int sBeg = cs0 + w * 32;
  const int sEnd = min(cs0 + (w + 1) * 32, kv_len);
#pragma unroll 2
  for (int s = sBeg; s < sEnd; ++s) {
    const float* krow;
    if (s < hist) {
      int blk = blk_off[(b << 5) + (s >> 6)];
      krow = k_cache + ((((size_t)blk * 64 + (s & 63)) * HKn + hk) << 8);
    } else {
      krow = kbuf + (((size_t)(q0 + s - hist) * HKn + hk) << 8);
    }
    const float* kp = krow + dgrp * 32;
    float sc = 0.f;
#pragma unroll
    for (int j = 0; j < 8; ++j) {
      float4 kf = *reinterpret_cast<const float4*>(kp + j * 4);
      sc = fmaf(qf[j].x, kf.x, sc);
      sc = fmaf(qf[j].y, kf.y, sc);
      sc = fmaf(qf[j].z, kf.z, sc);
      sc = fmaf(qf[j].w, kf.w, sc);
    }
    sc += __shfl_xor(sc, 8);
    sc += __shfl_xor(sc, 16);
    sc += __shfl_xor(sc, 32);
    if (lane < 8) {
      bool valid = (lane < nq) && ((s - hist) <= (lane >> 1));
      S_lds[s - cs0][lane] = valid ? sc : -1e30f;
    }
  }
  __syncthreads();

  // ---- phase 2: chunk-global softmax. thread tid: qv2 = tid&7, grp = tid>>3 (4 toks)
  const int qv2 = tid & 7;
  const int grp = tid >> 3;
  {
    float mloc = -1e30f;
#pragma unroll
    for (int t = 0; t < 4; ++t) mloc = fmaxf(mloc, S_lds[grp * 4 + t][qv2]);
    red[grp][qv2] = mloc;
  }
  __syncthreads();
  if (tid < 8) {
    float M = -1e30f;
#pragma unroll
    for (int i = 0; i < 32; ++i) M = fmaxf(M, red[i][tid]);
    Mg[tid] = M;
  }
  __syncthreads();
  {
    float M = Mg[qv2];
    float lloc = 0.f;
#pragma unroll
    for (int t = 0; t < 4; ++t) {
      int s = grp * 4 + t;
      float p = __expf(S_lds[s][qv2] - M);
      S_lds[s][qv2] = p;
      lloc += p;
    }
    red[grp][qv2] = lloc;
  }
  __syncthreads();
  if (tid < 8) {
    float L = 0.f;
#pragma unroll
    for (int i = 0; i < 32; ++i) L += red[i][tid];
    int pidx = (((b * HKn + hk) * NCHUNK + chunk) << 3) + tid;
    part_ml[pidx * 2] = Mg[tid];
    part_ml[pidx * 2 + 1] = L;
  }

  // ---- phase 3: PV. lane owns 4 dims (d = lane*4); wave owns 32 tokens; all 8 qv.
  float4 acc[8];
#pragma unroll
  for (int q = 0; q < 8; ++q) acc[q] = make_float4(0.f, 0.f, 0.f, 0.f);
  const int d4 = lane << 2;
#pragma unroll 2
  for (int s = sBeg; s < sEnd; ++s) {
    const float* vrow;
    if (s < hist) {
      int blk = blk_off[(b << 5) + (s >> 6)];
      vrow = v_cache + ((((size_t)blk * 64 + (s & 63)) * HKn + hk) << 8);
    } else {
      vrow = vbuf + (((size_t)(q0 + s - hist) * HKn + hk) << 8);
    }
    float4 vf = *reinterpret_cast<const float4*>(vrow + d4);
    int sl = s - cs0;
    float4 p0 = *reinterpret_cast<const float4*>(&S_lds[sl][0]);
    float4 p1 = *reinterpret_cast<const float4*>(&S_lds[sl][4]);
    acc[0].x = fmaf(p0.x, vf.x, acc[0].x); acc[0].y = fmaf(p0.x, vf.y, acc[0].y);
    acc[0].z = fmaf(p0.x, vf.z, acc[0].z); acc[0].w = fmaf(p0.x, vf.w, acc[0].w);
    acc[1].x = fmaf(p0.y, vf.x, acc[1].x); acc[1].y = fmaf(p0.y, vf.y, acc[1].y);
    acc[1].z = fmaf(p0.y, vf.z, acc[1].z); acc[1].w = fmaf(p0.y, vf.w, acc[1].w);
    acc[2].x = fmaf(p0.z, vf.x, acc[2].x); acc[2].y = fmaf(p0.z, vf.y, acc[2].y);
    acc[2].z = fmaf(p0.z, vf.z, acc[2].z); acc[2].w = fmaf(p0.z, vf.w, acc[2].w);
    acc[3].x = fmaf(p0.w, vf.x, acc[3].x); acc[3].y = fmaf(p0.w, vf.y, acc[3].y);
    acc[3].z = fmaf(p0.w, vf.z, acc[3].z); acc[3].w = fmaf(p0.w, vf.w, acc[3].w);
    acc[4].x = fmaf(p1.x, vf.x, acc[4].x); acc[4].y = fmaf(p1.x, vf.y, acc[4].y);
    acc[4].z = fmaf(p1.x, vf.z, acc[4].z); acc[4].w = fmaf(p1.x, vf.w, acc[4].w);
    acc[5].x = fmaf(p1.y, vf.x, acc[5].x); acc[5].y = fmaf(p1.y, vf.y, acc[5].y);
    acc[5].z = fmaf(p1.y, vf.z, acc[5].z); acc[5].w = fmaf(p1.y, vf.w, acc[5].w);
    acc[6].x = fmaf(p1.z, vf.x, acc[6].x); acc[6].y = fmaf(p1.z, vf.y, acc[6].y);
    acc[6].z = fmaf(p1.z, vf.z, acc[6].z); acc[6].w = fmaf(p1.z, vf.w, acc[6].w);
    acc[7].x = fmaf(p1.w, vf.x, acc[7].x); acc[7].y = fmaf(p1.w, vf.y, acc[7].y);
    acc[7].z = fmaf(p1.w, vf.z, acc[7].z); acc[7].w = fmaf(p1.w, vf.w, acc[7].w);
  }
#pragma unroll
  for (int q = 0; q < 8; ++q)
    *reinterpret_cast<float4*>(&o_lds[w][q][d4]) = acc[q];
  __syncthreads();

  // combine 4 wave-partials (same max within chunk -> plain sum)
  for (int q = 0; q < nq; ++q) {
    float o = o_lds[0][q][tid] + o_lds[1][q][tid] + o_lds[2][q][tid] + o_lds[3][q][tid];
    int pidx = (((b * HKn + hk) * NCHUNK + chunk) << 3) + q;
    part_o[(size_t)pidx * 256 + tid] = o;
  }
}

// ---------------- K4: combine chunk partials ----------------
// grid 1024 = b(16)*qtok(4)*h(16), block 64
__global__ __launch_bounds__(64) void k4_attn_reduce(
    const float* __restrict__ part_o, const float* __restrict__ part_ml,
    const int* __restrict__ q_start, const int* __restrict__ q_lens,
    const int* __restrict__ kv_lens, float* __restrict__ attn_out) {
  const int h = blockIdx.x & 15;
  const int qtok = (blockIdx.x >> 4) & 3;
  const int b = blockIdx.x >> 6;
  const int q_cnt = q_lens[b];
  if (qtok >= q_cnt) return;
  const int kv_len = kv_lens[b];
  const int nparts = (kv_len + CHUNKT - 1) >> 7;
  const int qv = qtok * 2 + (h & 1);
  const int hk = h >> 1;
  const int lane = threadIdx.x;
  const int pbase = ((b * HKn + hk) * NCHUNK) << 3;
  float M = -1e30f;
  for (int i = 0; i < nparts; ++i)
    M = fmaxf(M, part_ml[(pbase + (i << 3) + qv) * 2]);
  float4 o = make_float4(0.f, 0.f, 0.f, 0.f);
  float L = 0.f;
  for (int i = 0; i < nparts; ++i) {
    int pidx = pbase + (i << 3) + qv;
    float corr = __expf(part_ml[pidx * 2] - M);
    L += corr * part_ml[pidx * 2 + 1];
    float4 pv = *reinterpret_cast<const float4*>(&part_o[(size_t)pidx * 256 + (lane << 2)]);
    o.x = fmaf(corr, pv.x, o.x);
    o.y = fmaf(corr, pv.y, o.y);
    o.z = fmaf(corr, pv.z, o.z);
    o.w = fmaf(corr, pv.w, o.w);
  }
  float inv = 1.0f / L;
  int tr = q_start[b] + qtok;
  float4 res = make_float4(o.x * inv, o.y * inv, o.z * inv, o.w * inv);
  *reinterpret_cast<float4*>(&attn_out[((size_t)tr * HQn + h) * 256 + (lane << 2)]) = res;
}

// ---------------- K5: output GEMM partial (attn @ Wo) ----------------
// grid 384 = 12 col-tiles(256) * 32 k-splits(128), block 256
__global__ __launch_bounds__(256) void k5_out_gemm(
    const float* __restrict__ ain, const float* __restrict__ Wo,
    float* __restrict__ part2) {
  const int tile = blockIdx.x % 12;
  const int ks = blockIdx.x / 12;
  const int c0 = tile << 8;
  const int kbase = ks << 7;
  const int cq = (threadIdx.x & 63) << 2;
  const int r0 = (threadIdx.x >> 6) * 10;
  __shared__ float h_lds[64][40];
  float acc[10][4];
#pragma unroll
  for (int r = 0; r < 10; ++r) { acc[r][0]=0.f; acc[r][1]=0.f; acc[r][2]=0.f; acc[r][3]=0.f; }
  for (int kc = 0; kc < 128; kc += 64) {
    __syncthreads();
    for (int i = threadIdx.x; i < 2560; i += 256) {
      int kk = i / 40, t = i - kk * 40;
      h_lds[kk][t] = ain[(size_t)t * 4096 + kbase + kc + kk];
    }
    __syncthreads();
    const float* wp = Wo + (size_t)(kbase + kc) * 3072 + c0 + cq;
#pragma unroll 4
    for (int kk = 0; kk < 64; ++kk) {
      float4 w4 = *reinterpret_cast<const float4*>(wp + (size_t)kk * 3072);
#pragma unroll
      for (int r = 0; r < 10; ++r) {
        float h = h_lds[kk][r0 + r];
        acc[r][0] = fmaf(h, w4.x, acc[r][0]);
        acc[r][1] = fmaf(h, w4.y, acc[r][1]);
        acc[r][2] = fmaf(h, w4.z, acc[r][2]);
        acc[r][3] = fmaf(h, w4.w, acc[r][3]);
      }
    }
  }
#pragma unroll
  for (int r = 0; r < 10; ++r) {
    int t = r0 + r;
    float4 v = make_float4(acc[r][0], acc[r][1], acc[r][2], acc[r][3]);
    *reinterpret_cast<float4*>(&part2[(size_t)(ks * TT + t) * 3072 + c0 + cq]) = v;
  }
}

// ---------------- K6: final k-split reduce -> d_out ----------------
// grid 480, block 256  (40*3072 = 122880 outputs)
__global__ __launch_bounds__(256) void k6_final_reduce(
    const float* __restrict__ part2, float* __restrict__ out) {
  const int idx = blockIdx.x * 256 + threadIdx.x;
  float s = 0.f;
#pragma unroll
  for (int ks = 0; ks < 32; ++ks) s += part2[(size_t)ks * 122880 + idx];
  out[idx] = s;
}

extern "C" void kernel_launch(void* const* d_in, const int* in_sizes, int n_in,
                              void* d_out, int out_size, void* d_ws, size_t ws_size,
                              hipStream_t stream) {
  const float* hs       = (const float*)d_in[0];
  const float* Wq       = (const float*)d_in[1];
  const float* Wk       = (const float*)d_in[2];
  const float* Wv       = (const float*)d_in[3];
  const float* Wo       = (const float*)d_in[4];
  const float* k_cache  = (const float*)d_in[5];
  const float* v_cache  = (const float*)d_in[6];
  const float* inv_freq = (const float*)d_in[7];
  const int*   pos_ids  = (const int*)d_in[8];
  const int*   q_start  = (const int*)d_in[9];
  const int*   q_lens   = (const int*)d_in[10];
  const int*   kv_lens  = (const int*)d_in[11];
  const int*   blk_off  = (const int*)d_in[12];

  float* ws = (float*)d_ws;
  float* qbuf     = ws;                 // 40*4096          = 163840
  float* kbuf     = ws + 163840;        // 40*2048          =  81920
  float* vbuf     = ws + 245760;        // 40*2048          =  81920
  float* attn_out = ws + 327680;        // 40*4096          = 163840
  float* big      = ws + 491520;        // reused region (5242880 floats)
  float* part1    = big;                // 16*40*8192
  float* part_o   = big;                // 16384*256
  float* part_ml  = big + 4194304;      // 16384*2
  float* part2    = big;                // 32*40*3072
  float* out      = (float*)d_out;

  k1_qkv_gemm<<<512, 256, 0, stream>>>(hs, Wq, Wk, Wv, part1);
  k2_reduce_rope<<<1280, 256, 0, stream>>>(part1, inv_freq, pos_ids, qbuf, kbuf, vbuf);
  k3_attn_partial<<<2048, 256, 0, stream>>>(qbuf, kbuf, vbuf, k_cache, v_cache,
                                            blk_off, q_start, q_lens, kv_lens,
                                            part_o, part_ml);
  k4_attn_reduce<<<1024, 64, 0, stream>>>(part_o, part_ml, q_start, q_lens,
                                          kv_lens, attn_out);
  k5_out_gemm<<<384, 256, 0, stream>>>(attn_out, Wo, part2);
  k6_final_reduce<<<480, 256, 0, stream>>>(part2, out);
}

// Round 3
// 309.467 us; speedup vs baseline: 1.2499x; 1.1610x over previous
//
#include <hip/hip_runtime.h>
#include <math.h>

#define TT 40          // total query tokens (sum of q_seqlens)
#define NB 16          // batch
#define HQn 16         // query heads
#define HKn 8          // kv heads
#define Gn 2           // GQA group
#define Dn 256         // head dim
#define HID 3072
#define QKV_COLS 8192  // 4096 + 2048 + 2048
#define NCHUNK 16
#define CHUNKT 128

// ---------------- K1: QKV partial GEMM ----------------
// grid 512 = 32 col-tiles(256) * 16 k-splits(192), block 256
__global__ __launch_bounds__(256) void k1_qkv_gemm(
    const float* __restrict__ hs, const float* __restrict__ Wq,
    const float* __restrict__ Wk, const float* __restrict__ Wv,
    float* __restrict__ part1) {
  const int tile = blockIdx.x & 31;
  const int ks = blockIdx.x >> 5;
  const int c0 = tile << 8;
  const float* W; int ld, cw0;
  if (tile < 16)      { W = Wq; ld = 4096; cw0 = c0; }
  else if (tile < 24) { W = Wk; ld = 2048; cw0 = c0 - 4096; }
  else                { W = Wv; ld = 2048; cw0 = c0 - 6144; }
  const int kbase = ks * 192;
  const int cq = (threadIdx.x & 63) << 2;
  const int r0 = (threadIdx.x >> 6) * 10;
  __shared__ float h_lds[64][40];
  float acc[10][4];
#pragma unroll
  for (int r = 0; r < 10; ++r) { acc[r][0]=0.f; acc[r][1]=0.f; acc[r][2]=0.f; acc[r][3]=0.f; }
  for (int kc = 0; kc < 192; kc += 64) {
    __syncthreads();
    for (int i = threadIdx.x; i < 2560; i += 256) {
      int kk = i / 40, t = i - kk * 40;
      h_lds[kk][t] = hs[t * HID + kbase + kc + kk];
    }
    __syncthreads();
    const float* wp = W + (size_t)(kbase + kc) * ld + cw0 + cq;
#pragma unroll 4
    for (int kk = 0; kk < 64; ++kk) {
      float4 w4 = *reinterpret_cast<const float4*>(wp + (size_t)kk * ld);
#pragma unroll
      for (int r = 0; r < 10; ++r) {
        float h = h_lds[kk][r0 + r];
        acc[r][0] = fmaf(h, w4.x, acc[r][0]);
        acc[r][1] = fmaf(h, w4.y, acc[r][1]);
        acc[r][2] = fmaf(h, w4.z, acc[r][2]);
        acc[r][3] = fmaf(h, w4.w, acc[r][3]);
      }
    }
  }
#pragma unroll
  for (int r = 0; r < 10; ++r) {
    int t = r0 + r;
    float4 v = make_float4(acc[r][0], acc[r][1], acc[r][2], acc[r][3]);
    *reinterpret_cast<float4*>(&part1[(size_t)(ks * TT + t) * QKV_COLS + c0 + cq]) = v;
  }
}

// ---------------- K2: k-split reduce + RoPE ----------------
// grid 1280 = 40 tokens * 32 tiles, block 256
__global__ __launch_bounds__(256) void k2_reduce_rope(
    const float* __restrict__ part1, const float* __restrict__ inv_freq,
    const int* __restrict__ pos_ids,
    float* __restrict__ qbuf, float* __restrict__ kbuf, float* __restrict__ vbuf) {
  const int t = blockIdx.x >> 5;
  const int tile = blockIdx.x & 31;
  const int c = (tile << 8) + threadIdx.x;
  float s = 0.f;
#pragma unroll
  for (int ks = 0; ks < 16; ++ks) s += part1[(size_t)(ks * TT + t) * QKV_COLS + c];
  __shared__ float sl[256];
  sl[threadIdx.x] = s;
  __syncthreads();
  if (tile < 24) {   // q or k head: apply neox RoPE
    const int d = threadIdx.x;
    const int d2 = d & 127;
    float fr = (float)pos_ids[t] * inv_freq[d2];
    float cs = cosf(fr), sn = sinf(fr);
    float v = (d < 128) ? (sl[d] * cs - sl[d + 128] * sn)
                        : (sl[d] * cs + sl[d - 128] * sn);
    if (tile < 16) qbuf[t * 4096 + (tile << 8) + d] = v * 0.0625f;  // fold 1/sqrt(D)
    else           kbuf[t * 2048 + ((tile - 16) << 8) + d] = v;
  } else {
    vbuf[t * 2048 + ((tile - 24) << 8) + threadIdx.x] = s;
  }
}

// ---------------- K3: flash-decode attention partials ----------------
// 3-phase, register-pipelined loads, no dependent address chain.
// grid 2048 = b(16)*hk(8)*chunk(16 of 128 toks), block 256 (4 waves)
__global__ __launch_bounds__(256) void k3_attn_partial(
    const float* __restrict__ qbuf, const float* __restrict__ kbuf,
    const float* __restrict__ vbuf, const float* __restrict__ k_cache,
    const float* __restrict__ v_cache, const int* __restrict__ blk_off,
    const int* __restrict__ q_start, const int* __restrict__ q_lens,
    const int* __restrict__ kv_lens,
    float* __restrict__ part_o, float* __restrict__ part_ml) {
  const int chunk = blockIdx.x & 15;
  const int hk = (blockIdx.x >> 4) & 7;
  const int b = blockIdx.x >> 7;
  const int kv_len = kv_lens[b];
  const int cs0 = chunk * CHUNKT;
  if (cs0 >= kv_len) return;
  const int q_cnt = q_lens[b];
  const int hist = kv_len - q_cnt;
  const int q0 = q_start[b];
  const int nq = q_cnt * 2;

  __shared__ float S_lds[128][8];     // scores -> then p values (in place)
  __shared__ float red[32][8];
  __shared__ float Mg[8];
  __shared__ float o_lds[4][8][256];

  const int tid = threadIdx.x;
  const int w = tid >> 6;
  const int lane = tid & 63;

  // chunk spans exactly 2 cache blocks: preload both -> pure-arith addressing
  const int bi = (b << 5) + (cs0 >> 6);
  const int blk0v = blk_off[bi];
  const int blk1v = blk_off[bi + 1];
  const float* kb0  = k_cache + ((size_t)blk0v << 17) + ((size_t)hk << 8);
  const float* kb1  = k_cache + ((size_t)blk1v << 17) + ((size_t)hk << 8);
  const float* vb0  = v_cache + ((size_t)blk0v << 17) + ((size_t)hk << 8);
  const float* vb1  = v_cache + ((size_t)blk1v << 17) + ((size_t)hk << 8);
  const float* knew = kbuf + ((size_t)q0 << 11) + ((size_t)hk << 8);
  const float* vnew = vbuf + ((size_t)q0 << 11) + ((size_t)hk << 8);

  auto rowK = [&](int s) -> const float* {
    if (s < hist) {
      const float* base = (s & 64) ? kb1 : kb0;
      return base + ((size_t)(s & 63) << 11);
    }
    return knew + ((size_t)(s - hist) << 11);
  };
  auto rowV = [&](int s) -> const float* {
    if (s < hist) {
      const float* base = (s & 64) ? vb1 : vb0;
      return base + ((size_t)(s & 63) << 11);
    }
    return vnew + ((size_t)(s - hist) << 11);
  };

  // init scores to -inf (unwritten tail rows must be masked)
#pragma unroll
  for (int i = tid; i < 1024; i += 256) ((float*)S_lds)[i] = -1e30f;

  // ---- phase 1: scores. lane = qv(0..7) + 8*dgrp(0..7); wave handles 32 tokens.
  const int qv = lane & 7;
  const int dgrp = lane >> 3;
  const int qtok = min(qv >> 1, q_cnt - 1);
  const int g = qv & 1;
  float4 qf[8];
  {
    const float* qp = qbuf + (size_t)(q0 + qtok) * 4096 + (hk * Gn + g) * 256 + dgrp * 32;
#pragma unroll
    for (int j = 0; j < 8; ++j)
      qf[j] = *reinterpret_cast<const float4*>(qp + j * 4);
  }
  __syncthreads();

  const int sBeg = cs0 + w * 32;
  const int sEnd = min(cs0 + (w + 1) * 32, kv_len);

  {
    float4 A[8], B[8];
    auto loadK = [&](int sv, float4* R) {
      const float* p_ = rowK(sv) + (dgrp << 5);
#pragma unroll
      for (int j = 0; j < 8; ++j) R[j] = *reinterpret_cast<const float4*>(p_ + (j << 2));
    };
    auto scoreK = [&](int sv, const float4* R) {
      float sc = 0.f;
#pragma unroll
      for (int j = 0; j < 8; ++j) {
        sc = fmaf(qf[j].x, R[j].x, sc);
        sc = fmaf(qf[j].y, R[j].y, sc);
        sc = fmaf(qf[j].z, R[j].z, sc);
        sc = fmaf(qf[j].w, R[j].w, sc);
      }
      sc += __shfl_xor(sc, 8);
      sc += __shfl_xor(sc, 16);
      sc += __shfl_xor(sc, 32);
      if (lane < 8) {
        bool valid = (lane < nq) && ((sv - hist) <= (lane >> 1));
        S_lds[sv - cs0][lane] = valid ? sc : -1e30f;
      }
    };
    int s = sBeg;
    if (s < sEnd) loadK(s, A);
    for (; s + 1 < sEnd; ++s) {
      loadK(s + 1, B);          // next token's loads in flight under compute
      scoreK(s, A);
#pragma unroll
      for (int j = 0; j < 8; ++j) A[j] = B[j];
    }
    if (s < sEnd) scoreK(s, A);
  }
  __syncthreads();

  // ---- phase 2: chunk-global softmax. thread tid: qv2 = tid&7, grp = tid>>3 (4 toks)
  const int qv2 = tid & 7;
  const int grp = tid >> 3;
  {
    float mloc = -1e30f;
#pragma unroll
    for (int t = 0; t < 4; ++t) mloc = fmaxf(mloc, S_lds[grp * 4 + t][qv2]);
    red[grp][qv2] = mloc;
  }
  __syncthreads();
  if (tid < 8) {
    float M = -1e30f;
#pragma unroll
    for (int i = 0; i < 32; ++i) M = fmaxf(M, red[i][tid]);
    Mg[tid] = M;
  }
  __syncthreads();
  {
    float M = Mg[qv2];
    float lloc = 0.f;
#pragma unroll
    for (int t = 0; t < 4; ++t) {
      int s = grp * 4 + t;
      float p = __expf(S_lds[s][qv2] - M);
      S_lds[s][qv2] = p;
      lloc += p;
    }
    red[grp][qv2] = lloc;
  }
  __syncthreads();
  if (tid < 8) {
    float L = 0.f;
#pragma unroll
    for (int i = 0; i < 32; ++i) L += red[i][tid];
    int pidx = (((b * HKn + hk) * NCHUNK + chunk) << 3) + tid;
    part_ml[pidx * 2] = Mg[tid];
    part_ml[pidx * 2 + 1] = L;
  }

  // ---- phase 3: PV. lane owns 4 dims; wave owns 32 tokens; quad-pipelined V loads.
  float4 acc[8];
#pragma unroll
  for (int q = 0; q < 8; ++q) acc[q] = make_float4(0.f, 0.f, 0.f, 0.f);
  const int d4 = lane << 2;
  {
    auto pv1 = [&](int sv, const float4 vf) {
      const int sl = sv - cs0;
      float4 p0 = *reinterpret_cast<const float4*>(&S_lds[sl][0]);
      float4 p1 = *reinterpret_cast<const float4*>(&S_lds[sl][4]);
      float p_[8] = {p0.x, p0.y, p0.z, p0.w, p1.x, p1.y, p1.z, p1.w};
#pragma unroll
      for (int q = 0; q < 8; ++q) {
        acc[q].x = fmaf(p_[q], vf.x, acc[q].x);
        acc[q].y = fmaf(p_[q], vf.y, acc[q].y);
        acc[q].z = fmaf(p_[q], vf.z, acc[q].z);
        acc[q].w = fmaf(p_[q], vf.w, acc[q].w);
      }
    };
    float4 VA[4], VB[4];
    auto loadV4 = [&](int s0v, float4* R) {
#pragma unroll
      for (int t = 0; t < 4; ++t)
        R[t] = *reinterpret_cast<const float4*>(rowV(s0v + t) + d4);
    };
    const int n3 = sEnd - sBeg;
    const int nq4 = n3 >> 2;
    int s3 = sBeg;
    if (nq4 > 0) {
      loadV4(s3, VA);
      for (int it = 1; it < nq4; ++it) {
        loadV4(sBeg + (it << 2), VB);   // next quad in flight under compute
        pv1(s3, VA[0]); pv1(s3 + 1, VA[1]);
        pv1(s3 + 2, VA[2]); pv1(s3 + 3, VA[3]);
        s3 += 4;
#pragma unroll
        for (int t = 0; t < 4; ++t) VA[t] = VB[t];
      }
      pv1(s3, VA[0]); pv1(s3 + 1, VA[1]);
      pv1(s3 + 2, VA[2]); pv1(s3 + 3, VA[3]);
      s3 += 4;
    }
    for (; s3 < sEnd; ++s3) {
      float4 vf = *reinterpret_cast<const float4*>(rowV(s3) + d4);
      pv1(s3, vf);
    }
  }
#pragma unroll
  for (int q = 0; q < 8; ++q)
    *reinterpret_cast<float4*>(&o_lds[w][q][d4]) = acc[q];
  __syncthreads();

  // combine 4 wave-partials (same max within chunk -> plain sum)
  for (int q = 0; q < nq; ++q) {
    float o = o_lds[0][q][tid] + o_lds[1][q][tid] + o_lds[2][q][tid] + o_lds[3][q][tid];
    int pidx = (((b * HKn + hk) * NCHUNK + chunk) << 3) + q;
    part_o[(size_t)pidx * 256 + tid] = o;
  }
}

// ---------------- K4: combine chunk partials ----------------
// grid 1024 = b(16)*qtok(4)*h(16), block 64
__global__ __launch_bounds__(64) void k4_attn_reduce(
    const float* __restrict__ part_o, const float* __restrict__ part_ml,
    const int* __restrict__ q_start, const int* __restrict__ q_lens,
    const int* __restrict__ kv_lens, float* __restrict__ attn_out) {
  const int h = blockIdx.x & 15;
  const int qtok = (blockIdx.x >> 4) & 3;
  const int b = blockIdx.x >> 6;
  const int q_cnt = q_lens[b];
  if (qtok >= q_cnt) return;
  const int kv_len = kv_lens[b];
  const int nparts = (kv_len + CHUNKT - 1) >> 7;
  const int qv = qtok * 2 + (h & 1);
  const int hk = h >> 1;
  const int lane = threadIdx.x;
  const int pbase = ((b * HKn + hk) * NCHUNK) << 3;
  float2 mls[16];
#pragma unroll
  for (int i = 0; i < 16; ++i)
    if (i < nparts)
      mls[i] = *reinterpret_cast<const float2*>(&part_ml[(size_t)(pbase + (i << 3) + qv) * 2]);
  float M = -1e30f;
#pragma unroll
  for (int i = 0; i < 16; ++i)
    if (i < nparts) M = fmaxf(M, mls[i].x);
  float4 o = make_float4(0.f, 0.f, 0.f, 0.f);
  float L = 0.f;
#pragma unroll
  for (int i = 0; i < 16; ++i)
    if (i < nparts) {
      float corr = __expf(mls[i].x - M);
      L += corr * mls[i].y;
      float4 pv = *reinterpret_cast<const float4*>(
          &part_o[(size_t)(pbase + (i << 3) + qv) * 256 + (lane << 2)]);
      o.x = fmaf(corr, pv.x, o.x);
      o.y = fmaf(corr, pv.y, o.y);
      o.z = fmaf(corr, pv.z, o.z);
      o.w = fmaf(corr, pv.w, o.w);
    }
  float inv = 1.0f / L;
  int tr = q_start[b] + qtok;
  float4 res = make_float4(o.x * inv, o.y * inv, o.z * inv, o.w * inv);
  *reinterpret_cast<float4*>(&attn_out[((size_t)tr * HQn + h) * 256 + (lane << 2)]) = res;
}

// ---------------- K5: output GEMM partial (attn @ Wo) ----------------
// grid 384 = 12 col-tiles(256) * 32 k-splits(128), block 256
__global__ __launch_bounds__(256) void k5_out_gemm(
    const float* __restrict__ ain, const float* __restrict__ Wo,
    float* __restrict__ part2) {
  const int tile = blockIdx.x % 12;
  const int ks = blockIdx.x / 12;
  const int c0 = tile << 8;
  const int kbase = ks << 7;
  const int cq = (threadIdx.x & 63) << 2;
  const int r0 = (threadIdx.x >> 6) * 10;
  __shared__ float h_lds[64][40];
  float acc[10][4];
#pragma unroll
  for (int r = 0; r < 10; ++r) { acc[r][0]=0.f; acc[r][1]=0.f; acc[r][2]=0.f; acc[r][3]=0.f; }
  for (int kc = 0; kc < 128; kc += 64) {
    __syncthreads();
    for (int i = threadIdx.x; i < 2560; i += 256) {
      int kk = i / 40, t = i - kk * 40;
      h_lds[kk][t] = ain[(size_t)t * 4096 + kbase + kc + kk];
    }
    __syncthreads();
    const float* wp = Wo + (size_t)(kbase + kc) * 3072 + c0 + cq;
#pragma unroll 4
    for (int kk = 0; kk < 64; ++kk) {
      float4 w4 = *reinterpret_cast<const float4*>(wp + (size_t)kk * 3072);
#pragma unroll
      for (int r = 0; r < 10; ++r) {
        float h = h_lds[kk][r0 + r];
        acc[r][0] = fmaf(h, w4.x, acc[r][0]);
        acc[r][1] = fmaf(h, w4.y, acc[r][1]);
        acc[r][2] = fmaf(h, w4.z, acc[r][2]);
        acc[r][3] = fmaf(h, w4.w, acc[r][3]);
      }
    }
  }
#pragma unroll
  for (int r = 0; r < 10; ++r) {
    int t = r0 + r;
    float4 v = make_float4(acc[r][0], acc[r][1], acc[r][2], acc[r][3]);
    *reinterpret_cast<float4*>(&part2[(size_t)(ks * TT + t) * 3072 + c0 + cq]) = v;
  }
}

// ---------------- K6: final k-split reduce -> d_out ----------------
// grid 480, block 256  (40*3072 = 122880 outputs)
__global__ __launch_bounds__(256) void k6_final_reduce(
    const float* __restrict__ part2, float* __restrict__ out) {
  const int idx = blockIdx.x * 256 + threadIdx.x;
  float s = 0.f;
#pragma unroll
  for (int ks = 0; ks < 32; ++ks) s += part2[(size_t)ks * 122880 + idx];
  out[idx] = s;
}

extern "C" void kernel_launch(void* const* d_in, const int* in_sizes, int n_in,
                              void* d_out, int out_size, void* d_ws, size_t ws_size,
                              hipStream_t stream) {
  const float* hs       = (const float*)d_in[0];
  const float* Wq       = (const float*)d_in[1];
  const float* Wk       = (const float*)d_in[2];
  const float* Wv       = (const float*)d_in[3];
  const float* Wo       = (const float*)d_in[4];
  const float* k_cache  = (const float*)d_in[5];
  const float* v_cache  = (const float*)d_in[6];
  const float* inv_freq = (const float*)d_in[7];
  const int*   pos_ids  = (const int*)d_in[8];
  const int*   q_start  = (const int*)d_in[9];
  const int*   q_lens   = (const int*)d_in[10];
  const int*   kv_lens  = (const int*)d_in[11];
  const int*   blk_off  = (const int*)d_in[12];

  float* ws = (float*)d_ws;
  float* qbuf     = ws;                 // 40*4096          = 163840
  float* kbuf     = ws + 163840;        // 40*2048          =  81920
  float* vbuf     = ws + 245760;        // 40*2048          =  81920
  float* attn_out = ws + 327680;        // 40*4096          = 163840
  float* big      = ws + 491520;        // reused region (5242880 floats)
  float* part1    = big;                // 16*40*8192
  float* part_o   = big;                // 16384*256
  float* part_ml  = big + 4194304;      // 16384*2
  float* part2    = big;                // 32*40*3072
  float* out      = (float*)d_out;

  k1_qkv_gemm<<<512, 256, 0, stream>>>(hs, Wq, Wk, Wv, part1);
  k2_reduce_rope<<<1280, 256, 0, stream>>>(part1, inv_freq, pos_ids, qbuf, kbuf, vbuf);
  k3_attn_partial<<<2048, 256, 0, stream>>>(qbuf, kbuf, vbuf, k_cache, v_cache,
                                            blk_off, q_start, q_lens, kv_lens,
                                            part_o, part_ml);
  k4_attn_reduce<<<1024, 64, 0, stream>>>(part_o, part_ml, q_start, q_lens,
                                          kv_lens, attn_out);
  k5_out_gemm<<<384, 256, 0, stream>>>(attn_out, Wo, part2);
  k6_final_reduce<<<480, 256, 0, stream>>>(part2, out);
}